// Round 6
// baseline (1244.199 us; speedup 1.0000x reference)
//
#include <hip/hip_runtime.h>
#include <math.h>

// EEG connectivity: B=4, C=64, T=2048, FS=256, 6 bands, 7 features.
__constant__ int c_klo[6] = {4, 4, 32, 64, 104, 240};
__constant__ int c_nk[6]  = {357, 29, 33, 41, 137, 121};

#define PI2_N 0.0030679615757712823f /* 2*pi/2048 */

// ---------------- K1: band-limited forward DFT of both inputs.
// coef[(bside*357+kidx)*64+ch] = F[k] (float2); pwr = |F|^2 (float).
__global__ __launch_bounds__(256) void k_dft(const float* __restrict__ e1,
                                             const float* __restrict__ e2,
                                             float2* __restrict__ coef,
                                             float* __restrict__ pwr) {
  __shared__ float xs[2048];
  __shared__ float red[4][64][2];
  int sig = blockIdx.x;              // 512 = b(4) x side(2) x ch(64)
  int b = sig >> 7, side = (sig >> 6) & 1, ch = sig & 63;
  int bside = b * 2 + side;
  const float* src = (side ? e2 : e1) + (size_t)(b * 64 + ch) * 2048;
  for (int q = 0; q < 2; ++q) {
    int i4 = q * 256 + threadIdx.x;
    ((float4*)xs)[i4] = ((const float4*)src)[i4];
  }
  __syncthreads();
  int binlane = threadIdx.x & 63, tch = threadIdx.x >> 6;
  int t0 = tch << 9;
  const float* xp = xs + t0;
  for (int rnd = 0; rnd < 6; ++rnd) {
    int kidx = rnd * 64 + binlane;
    int k = kidx + 4;
    float wr, wi, sr, si;
    sincosf(-(float)((k * t0) & 2047) * PI2_N, &wi, &wr);
    sincosf(-(float)k * PI2_N, &si, &sr);
    float are = 0.f, aim = 0.f;
    for (int tt = 0; tt < 512; tt += 4) {
      float4 xv = *(const float4*)(xp + tt);
      float nr, ni;
      are = fmaf(xv.x, wr, are); aim = fmaf(xv.x, wi, aim);
      nr = fmaf(wr, sr, -(wi * si)); ni = fmaf(wr, si, wi * sr); wr = nr; wi = ni;
      are = fmaf(xv.y, wr, are); aim = fmaf(xv.y, wi, aim);
      nr = fmaf(wr, sr, -(wi * si)); ni = fmaf(wr, si, wi * sr); wr = nr; wi = ni;
      are = fmaf(xv.z, wr, are); aim = fmaf(xv.z, wi, aim);
      nr = fmaf(wr, sr, -(wi * si)); ni = fmaf(wr, si, wi * sr); wr = nr; wi = ni;
      are = fmaf(xv.w, wr, are); aim = fmaf(xv.w, wi, aim);
      nr = fmaf(wr, sr, -(wi * si)); ni = fmaf(wr, si, wi * sr); wr = nr; wi = ni;
    }
    red[tch][binlane][0] = are;
    red[tch][binlane][1] = aim;
    __syncthreads();
    if (tch == 0 && kidx < 357) {
      float rr = red[0][binlane][0] + red[1][binlane][0] + red[2][binlane][0] + red[3][binlane][0];
      float ri = red[0][binlane][1] + red[1][binlane][1] + red[2][binlane][1] + red[3][binlane][1];
      int a = (bside * 357 + kidx) * 64 + ch;
      coef[a] = make_float2(rr, ri);
      pwr[a] = rr * rr + ri * ri;
    }
    __syncthreads();
  }
}

// ---------------- K2: inverse band DFT. F staged in LDS (35-bin chunks),
// register-rotated twiddles re-seeded per chunk. lanes = t, 4 waves x 16 ch.
// fields[((band*8+bside)*2 + f)*131072 + t*64 + ch], f: 0=re 1=im (scaled 2/T)
#define CS 35
__global__ __launch_bounds__(256, 2) void k_analytic(const float* __restrict__ coef,
                                                     float* __restrict__ fields) {
  __shared__ float Fs[CS * 128];   // 17.9 KB
  __shared__ float Lt[2][64][65];  // 33.3 KB
  int tchunk = blockIdx.x, bside = blockIdx.y, split = blockIdx.z;
  int lane = threadIdx.x & 63;
  int ch0 = (threadIdx.x >> 6) << 4;
  int t = tchunk * 64 + lane;
  float Rr, Ri; sincosf((float)t * PI2_N, &Ri, &Rr);  // R = e^{+i*2pi*t/2048}
  int bandList[3], ksList[3], nkList[3], nb;
  if (split == 0) {
    nb = 3;
    bandList[0] = 1; ksList[0] = 4;  nkList[0] = 29;
    bandList[1] = 2; ksList[1] = 32; nkList[1] = 33;
    bandList[2] = 3; ksList[2] = 64; nkList[2] = 41;
  } else if (split == 1) {
    nb = 1; bandList[0] = 4; ksList[0] = 104; nkList[0] = 137;
  } else {
    nb = 1; bandList[0] = 5; ksList[0] = 240; nkList[0] = 121;
  }
  for (int bi = 0; bi < nb; ++bi) {
    int band = bandList[bi], ks = ksList[bi], nk = nkList[bi];
    float ar[16], ai[16];
#pragma unroll
    for (int c = 0; c < 16; ++c) { ar[c] = 0.f; ai[c] = 0.f; }
    for (int c0 = 0; c0 < nk; c0 += CS) {
      int kc = min(CS, nk - c0);
      __syncthreads();
      {
        const float4* srcp = (const float4*)(coef + (size_t)(bside * 357 + (ks - 4) + c0) * 128);
        for (int idx = threadIdx.x; idx < kc * 32; idx += 256)
          ((float4*)Fs)[idx] = srcp[idx];
      }
      __syncthreads();
      float Wr, Wi; { int m = ((ks + c0) * t) & 2047; sincosf((float)m * PI2_N, &Wi, &Wr); }
      const float* Fb = Fs + ch0 * 2;
#pragma unroll 2
      for (int kk = 0; kk < kc; ++kk) {
        const float* F = Fb + kk * 128;
#pragma unroll
        for (int q = 0; q < 8; ++q) {
          float4 Fv = *(const float4*)(F + q * 4);
          ar[2 * q]     = fmaf(Fv.x, Wr, ar[2 * q]);     ar[2 * q]     = fmaf(-Fv.y, Wi, ar[2 * q]);
          ai[2 * q]     = fmaf(Fv.x, Wi, ai[2 * q]);     ai[2 * q]     = fmaf( Fv.y, Wr, ai[2 * q]);
          ar[2 * q + 1] = fmaf(Fv.z, Wr, ar[2 * q + 1]); ar[2 * q + 1] = fmaf(-Fv.w, Wi, ar[2 * q + 1]);
          ai[2 * q + 1] = fmaf(Fv.z, Wi, ai[2 * q + 1]); ai[2 * q + 1] = fmaf( Fv.w, Wr, ai[2 * q + 1]);
        }
        float nr = fmaf(Wr, Rr, -(Wi * Ri));
        float ni = fmaf(Wr, Ri, Wi * Rr);
        Wr = nr; Wi = ni;
      }
    }
    __syncthreads();
#pragma unroll
    for (int c = 0; c < 16; ++c) {
      Lt[0][ch0 + c][lane] = ar[c] * (1.f / 1024.f);
      Lt[1][ch0 + c][lane] = ai[c] * (1.f / 1024.f);
    }
    __syncthreads();
    size_t base = (size_t)((band * 8 + bside) * 2) * 131072 + (size_t)tchunk * 4096;
    for (int idx = threadIdx.x; idx < 2048; idx += 256) {
      int fi = idx >> 10, r = idx & 1023, tt = r >> 4, c4 = (r & 15) * 4;
      float4 v = make_float4(Lt[fi][c4][tt], Lt[fi][c4 + 1][tt], Lt[fi][c4 + 2][tt], Lt[fi][c4 + 3][tt]);
      *(float4*)(fields + base + (size_t)fi * 131072 + tt * 64 + c4) = v;
    }
  }
}

// ---------------- K2b: band 0 = sum(bands 1..5) - duplicated boundary bins.
__global__ __launch_bounds__(256) void k_band0(const float* __restrict__ fields_in,
                                               const float* __restrict__ coef,
                                               float* __restrict__ fields) {
  int idx = blockIdx.x * 256 + threadIdx.x;  // 1048576 = 8 bsd x 2048 t x 64 ch
  int ch = idx & 63, t = (idx >> 6) & 2047, bsd = idx >> 17;
  size_t o = (size_t)t * 64 + ch;
  float re = 0.f, im = 0.f;
#pragma unroll
  for (int b = 1; b <= 5; ++b) {
    re += fields_in[(size_t)((b * 8 + bsd) * 2 + 0) * 131072 + o];
    im += fields_in[(size_t)((b * 8 + bsd) * 2 + 1) * 131072 + o];
  }
  const int dk[4] = {32, 64, 104, 240};
#pragma unroll
  for (int q = 0; q < 4; ++q) {
    int k = dk[q];
    const float* F = coef + ((size_t)(bsd * 357 + (k - 4)) * 64 + ch) * 2;
    float fx = F[0], fy = F[1];
    float s, c; sincosf((float)((k * t) & 2047) * PI2_N, &s, &c);
    re -= (fx * c - fy * s) * (1.f / 1024.f);
    im -= (fx * s + fy * c) * (1.f / 1024.f);
  }
  fields[(size_t)(bsd * 2 + 0) * 131072 + o] = re;
  fields[(size_t)(bsd * 2 + 1) * 131072 + o] = im;
}

// ---------------- K4: fused pairwise sums; trig expansion on the fly.
// Grid (32, 24): 64 t-samples per block. LDS rows padded to 68 (bank-safe).
// part[((bb*32+ts)*7 + a)*4096 + i*64 + j]
__global__ __launch_bounds__(256, 4) void k_pairs(const float* __restrict__ fields,
                                                  float* __restrict__ part) {
  __shared__ float le[2][4][16][68];  // [side][f][tt][ch pad 68]  (34.8 KB)
  int ts = blockIdx.x, bb = blockIdx.y;
  int band = bb >> 2, b = bb & 3;
  int tid = threadIdx.x;
  int ti = tid >> 4, tj = tid & 15;
  const float* bi = fields + (size_t)((band * 8 + b * 2 + 0) * 2) * 131072;
  const float* bj = fields + (size_t)((band * 8 + b * 2 + 1) * 2) * 131072;
  float acc[7][4][4];
#pragma unroll
  for (int a = 0; a < 7; ++a)
#pragma unroll
    for (int il = 0; il < 4; ++il)
#pragma unroll
      for (int jl = 0; jl < 4; ++jl) acc[a][il][jl] = 0.f;
  int lside = tid >> 7, lr = tid & 127, ltt = lr >> 3, lc8 = (lr & 7) * 8;
  const float* lbase = lside ? bj : bi;
  int tb = ts * 64;
  for (int sub = 0; sub < 4; ++sub) {
    int t0 = tb + sub * 16;
    {
      const float* rp = lbase + (size_t)(t0 + ltt) * 64 + lc8;
      float4 reA = *(const float4*)rp;
      float4 reB = *(const float4*)(rp + 4);
      float4 imA = *(const float4*)(rp + 131072);
      float4 imB = *(const float4*)(rp + 131072 + 4);
      float re8[8] = {reA.x, reA.y, reA.z, reA.w, reB.x, reB.y, reB.z, reB.w};
      float im8[8] = {imA.x, imA.y, imA.z, imA.w, imB.x, imB.y, imB.z, imB.w};
#pragma unroll
      for (int e = 0; e < 8; ++e) {
        float re = re8[e], im = im8[e];
        float mag2 = fmaf(re, re, im * im);
        float rinv = mag2 > 0.f ? rsqrtf(mag2) : 0.f;
        float cc = mag2 > 0.f ? re * rinv : 1.f;
        float ss = im * rinv;
        float ph = atan2f(im, re);
        le[lside][0][ltt][lc8 + e] = ph;
        le[lside][1][ltt][lc8 + e] = cc;
        le[lside][2][ltt][lc8 + e] = ss;
        le[lside][3][ltt][lc8 + e] = re;
      }
    }
    __syncthreads();
#pragma unroll 2
    for (int tt = 0; tt < 16; ++tt) {
      float4 vph1 = *(const float4*)&le[0][0][tt][ti * 4];
      float4 vc1 = *(const float4*)&le[0][1][tt][ti * 4];
      float4 vs1 = *(const float4*)&le[0][2][tt][ti * 4];
      float4 vf1 = *(const float4*)&le[0][3][tt][ti * 4];
      float4 vph2 = *(const float4*)&le[1][0][tt][tj * 4];
      float4 vc2 = *(const float4*)&le[1][1][tt][tj * 4];
      float4 vs2 = *(const float4*)&le[1][2][tt][tj * 4];
      float4 vf2 = *(const float4*)&le[1][3][tt][tj * 4];
      float ph1a[4] = {vph1.x, vph1.y, vph1.z, vph1.w};
      float c1a[4] = {vc1.x, vc1.y, vc1.z, vc1.w};
      float s1a[4] = {vs1.x, vs1.y, vs1.z, vs1.w};
      float f1a[4] = {vf1.x, vf1.y, vf1.z, vf1.w};
      float ph2a[4] = {vph2.x, vph2.y, vph2.z, vph2.w};
      float c2a[4] = {vc2.x, vc2.y, vc2.z, vc2.w};
      float s2a[4] = {vs2.x, vs2.y, vs2.z, vs2.w};
      float f2a[4] = {vf2.x, vf2.y, vf2.z, vf2.w};
      float p1a[4] = {f1a[0] * f1a[0], f1a[1] * f1a[1], f1a[2] * f1a[2], f1a[3] * f1a[3]};
      float p2a[4] = {f2a[0] * f2a[0], f2a[1] * f2a[1], f2a[2] * f2a[2], f2a[3] * f2a[3]};
#pragma unroll
      for (int il = 0; il < 4; ++il) {
#pragma unroll
        for (int jl = 0; jl < 4; ++jl) {
          float pd = ph1a[il] - ph2a[jl];
          float sg = pd > 0.f ? 1.f : -1.f;
          acc[2][il][jl] += sg;
          acc[3][il][jl] = fmaf(sg, p1a[il], acc[3][il][jl]);
          acc[4][il][jl] = fmaf(sg, p2a[jl], acc[4][il][jl]);
          acc[5][il][jl] += fabsf(pd);
          acc[0][il][jl] = fmaf(c1a[il], c2a[jl], acc[0][il][jl]);
          acc[0][il][jl] = fmaf(s1a[il], s2a[jl], acc[0][il][jl]);
          acc[1][il][jl] = fmaf(s1a[il], c2a[jl], acc[1][il][jl]);
          acc[1][il][jl] = fmaf(-c1a[il], s2a[jl], acc[1][il][jl]);
          acc[6][il][jl] = fmaf(p1a[il], p2a[jl], acc[6][il][jl]);
        }
      }
    }
    __syncthreads();
  }
  int pb = (bb * 32 + ts) * 7;
#pragma unroll
  for (int a = 0; a < 7; ++a)
#pragma unroll
    for (int il = 0; il < 4; ++il) {
      int ro = (ti * 4 + il) * 64 + tj * 4;
      *(float4*)&part[(size_t)(pb + a) * 4096 + ro] =
          make_float4(acc[a][il][0], acc[a][il][1], acc[a][il][2], acc[a][il][3]);
    }
}

// ---------------- K3: per-signal stats: Sum f^2 (Parseval), Sum f^4 (from fields).
__global__ __launch_bounds__(256) void k_stats(const float* __restrict__ fields,
                                               const float* __restrict__ pwr,
                                               float* __restrict__ stats) {
  __shared__ float red[256];
  int bb = blockIdx.x;               // 48 = band(6) x bsd(8)
  int band = bb >> 3, bsd = bb & 7;
  int ch = threadIdx.x & 63, tq = threadIdx.x >> 6;
  const float* fp = fields + (size_t)((band * 8 + bsd) * 2) * 131072 + (size_t)tq * 512 * 64 + ch;
  float s4 = 0.f;
  for (int tt = 0; tt < 512; ++tt) { float v = fp[tt * 64]; float p = v * v; s4 = fmaf(p, p, s4); }
  red[threadIdx.x] = s4;
  __syncthreads();
  if (tq == 0) {
    float sq = red[ch] + red[64 + ch] + red[128 + ch] + red[192 + ch];
    int kl = c_klo[band] - 4, nk = c_nk[band];
    const float* pp = pwr + (size_t)(bsd * 357 + kl) * 64 + ch;
    float sp = 0.f;
    for (int kkq = 0; kkq < nk; ++kkq) sp += pp[kkq * 64];
    sp *= (1.f / 1024.f);
    int o = ((band * 8 + bsd) * 64 + ch) * 2;
    stats[o] = sp;
    stats[o + 1] = sq;
  }
}

// ---------------- K5: reduce partials + coherence + spectral tcorr + finalize.
__global__ __launch_bounds__(256) void k_final(const float* __restrict__ part,
                                               const float* __restrict__ stats,
                                               const float* __restrict__ pwr,
                                               const float* __restrict__ coef,
                                               float* __restrict__ out) {
  int gid = blockIdx.x * 256 + threadIdx.x;  // 98304 = 24*4096
  int bb = gid >> 12, rem = gid & 4095;
  int band = bb >> 2, b = bb & 3;
  int i = rem >> 6, j = rem & 63;
  float S[7];
#pragma unroll
  for (int a = 0; a < 7; ++a) S[a] = 0.f;
  const float* pp = part + (size_t)bb * 32 * 7 * 4096 + rem;
  for (int ts = 0; ts < 32; ++ts)
#pragma unroll
    for (int a = 0; a < 7; ++a) S[a] += pp[(ts * 7 + a) * 4096];
  const float* st1 = stats + (size_t)((band * 8 + b * 2 + 0) * 64 + i) * 2;
  const float* st2 = stats + (size_t)((band * 8 + b * 2 + 1) * 64 + j) * 2;
  float sp1 = st1[0], sq1 = st1[1];
  float sp2 = st2[0], sq2 = st2[1];
  const float T = 2048.f, Ti = 1.f / 2048.f, Vi = 1.f / 2047.f;
  float plv = sqrtf(S[0] * S[0] + S[1] * S[1]) * Ti;
  float pli = fabsf(S[2]) * Ti;
  float wpli = fabsf(0.5f * (S[3] + S[4])) / (0.5f * (sp1 + sp2) + 1e-8f);
  int kl = c_klo[band] - 4, n = c_nk[band];
  const float* P1 = pwr + (size_t)((b * 2 + 0) * 357 + kl) * 64 + i;
  const float* P2 = pwr + (size_t)((b * 2 + 1) * 357 + kl) * 64 + j;
  const float* C1 = coef + ((size_t)((b * 2 + 0) * 357 + kl) * 64 + i) * 2;
  const float* C2 = coef + ((size_t)((b * 2 + 1) * 357 + kl) * 64 + j) * 2;
  float coh = 0.f, cross = 0.f;
  for (int kkq = 0; kkq < n; ++kkq) {
    float r = P1[kkq * 64] * P2[kkq * 64];
    coh += __fdividef(r, r + 1e-8f);
    float2 a = *(const float2*)(C1 + kkq * 128);
    float2 c = *(const float2*)(C2 + kkq * 128);
    cross = fmaf(a.x, c.x, fmaf(a.y, c.y, cross));
  }
  coh *= (1.f / 1025.f);
  float mp1 = sp1 * Ti, mp2 = sp2 * Ti;
  float sd1 = sqrtf(fmaxf((sq1 - T * mp1 * mp1) * Vi, 0.f));
  float sd2 = sqrtf(fmaxf((sq2 - T * mp2 * mp2) * Vi, 0.f));
  float pcorr = (S[6] - T * mp1 * mp2) / ((sd1 + 1e-8f) * (sd2 + 1e-8f)) * Ti;
  float phd = S[5] * Ti;
  float se1 = sqrtf(sp1 * Vi);
  float se2 = sqrtf(sp2 * Vi);
  float tcorr = (cross * (1.f / 1024.f)) / ((se1 + 1e-8f) * (se2 + 1e-8f)) * Ti;
  size_t ob = (size_t)((b * 6 + band) * 7) * 4096 + rem;
  out[ob] = plv;
  out[ob + 4096] = pli;
  out[ob + 2 * 4096] = wpli;
  out[ob + 3 * 4096] = coh;
  out[ob + 4 * 4096] = pcorr;
  out[ob + 5 * 4096] = phd;
  out[ob + 6 * 4096] = tcorr;
}

extern "C" void kernel_launch(void* const* d_in, const int* in_sizes, int n_in,
                              void* d_out, int out_size, void* d_ws, size_t ws_size,
                              hipStream_t stream) {
  const float* e1 = (const float*)d_in[0];
  const float* e2 = (const float*)d_in[1];
  float* out = (float*)d_out;
  char* ws = (char*)d_ws;
  size_t off = 0;
  auto alloc = [&](size_t bytes) -> void* {
    void* p = ws + off;
    off += (bytes + 255) & ~(size_t)255;
    return p;
  };
  float2* coef = (float2*)alloc((size_t)8 * 357 * 64 * 8);          // 1.46 MB
  float* pwr = (float*)alloc((size_t)8 * 357 * 64 * 4);             // 0.73 MB
  float* fields = (float*)alloc((size_t)6 * 8 * 2 * 131072 * 4);    // 50.3 MB
  float* stats = (float*)alloc((size_t)6 * 8 * 64 * 2 * 4);         // 25 KB
  float* part = (float*)alloc((size_t)24 * 32 * 7 * 4096 * 4);      // 88.1 MB
  (void)in_sizes; (void)n_in; (void)out_size; (void)ws_size;       // total ~140.6 MB

  hipLaunchKernelGGL(k_dft, dim3(512), dim3(256), 0, stream, e1, e2, coef, pwr);
  hipLaunchKernelGGL(k_analytic, dim3(32, 8, 3), dim3(256), 0, stream, (const float*)coef, fields);
  hipLaunchKernelGGL(k_band0, dim3(4096), dim3(256), 0, stream, fields, (const float*)coef, fields);
  hipLaunchKernelGGL(k_pairs, dim3(32, 24), dim3(256), 0, stream, fields, part);
  hipLaunchKernelGGL(k_stats, dim3(48), dim3(256), 0, stream, fields, pwr, stats);
  hipLaunchKernelGGL(k_final, dim3(384), dim3(256), 0, stream, part, stats, pwr, (const float*)coef, out);
}

// Round 7
// 340.654 us; speedup vs baseline: 3.6524x; 3.6524x over previous
//
#include <hip/hip_runtime.h>
#include <math.h>

// EEG connectivity: B=4, C=64, T=2048, FS=256, 6 bands, 7 features.
__constant__ int c_klo[6] = {4, 4, 32, 64, 104, 240};
__constant__ int c_nk[6]  = {357, 29, 33, 41, 137, 121};

#define PI2_N 0.0030679615757712823f /* 2*pi/2048 */

// ---------------- K1: band-limited forward DFT of both inputs.
// coef[(bside*357+kidx)*64+ch] = F[k] (float2); pwr = |F|^2 (float).
__global__ __launch_bounds__(256) void k_dft(const float* __restrict__ e1,
                                             const float* __restrict__ e2,
                                             float2* __restrict__ coef,
                                             float* __restrict__ pwr) {
  __shared__ float xs[2048];
  __shared__ float red[4][64][2];
  int sig = blockIdx.x;              // 512 = b(4) x side(2) x ch(64)
  int b = sig >> 7, side = (sig >> 6) & 1, ch = sig & 63;
  int bside = b * 2 + side;
  const float* src = (side ? e2 : e1) + (size_t)(b * 64 + ch) * 2048;
  for (int q = 0; q < 2; ++q) {
    int i4 = q * 256 + threadIdx.x;
    ((float4*)xs)[i4] = ((const float4*)src)[i4];
  }
  __syncthreads();
  int binlane = threadIdx.x & 63, tch = threadIdx.x >> 6;
  int t0 = tch << 9;
  const float* xp = xs + t0;
  for (int rnd = 0; rnd < 6; ++rnd) {
    int kidx = rnd * 64 + binlane;
    int k = kidx + 4;
    float wr, wi, sr, si;
    sincosf(-(float)((k * t0) & 2047) * PI2_N, &wi, &wr);
    sincosf(-(float)k * PI2_N, &si, &sr);
    float are = 0.f, aim = 0.f;
    for (int tt = 0; tt < 512; tt += 4) {
      float4 xv = *(const float4*)(xp + tt);
      float nr, ni;
      are = fmaf(xv.x, wr, are); aim = fmaf(xv.x, wi, aim);
      nr = fmaf(wr, sr, -(wi * si)); ni = fmaf(wr, si, wi * sr); wr = nr; wi = ni;
      are = fmaf(xv.y, wr, are); aim = fmaf(xv.y, wi, aim);
      nr = fmaf(wr, sr, -(wi * si)); ni = fmaf(wr, si, wi * sr); wr = nr; wi = ni;
      are = fmaf(xv.z, wr, are); aim = fmaf(xv.z, wi, aim);
      nr = fmaf(wr, sr, -(wi * si)); ni = fmaf(wr, si, wi * sr); wr = nr; wi = ni;
      are = fmaf(xv.w, wr, are); aim = fmaf(xv.w, wi, aim);
      nr = fmaf(wr, sr, -(wi * si)); ni = fmaf(wr, si, wi * sr); wr = nr; wi = ni;
    }
    red[tch][binlane][0] = are;
    red[tch][binlane][1] = aim;
    __syncthreads();
    if (tch == 0 && kidx < 357) {
      float rr = red[0][binlane][0] + red[1][binlane][0] + red[2][binlane][0] + red[3][binlane][0];
      float ri = red[0][binlane][1] + red[1][binlane][1] + red[2][binlane][1] + red[3][binlane][1];
      int a = (bside * 357 + kidx) * 64 + ch;
      coef[a] = make_float2(rr, ri);
      pwr[a] = rr * rr + ri * ri;
    }
    __syncthreads();
  }
}

// ---------------- K2: inverse band DFT. F staged in LDS (35-bin chunks),
// register-rotated twiddles re-seeded per chunk. lanes = t, 4 waves x 16 ch.
// fields[((band*8+bside)*2 + f)*131072 + t*64 + ch], f: 0=re 1=im (scaled 2/T)
#define CS 35
__global__ __launch_bounds__(256, 2) void k_analytic(const float* __restrict__ coef,
                                                     float* __restrict__ fields) {
  __shared__ float Fs[CS * 128];   // 17.9 KB
  __shared__ float Lt[2][64][65];  // 33.3 KB
  int tchunk = blockIdx.x, bside = blockIdx.y, split = blockIdx.z;
  int lane = threadIdx.x & 63;
  int ch0 = (threadIdx.x >> 6) << 4;
  int t = tchunk * 64 + lane;
  float Rr, Ri; sincosf((float)t * PI2_N, &Ri, &Rr);  // R = e^{+i*2pi*t/2048}
  int bandList[3], ksList[3], nkList[3], nb;
  if (split == 0) {
    nb = 3;
    bandList[0] = 1; ksList[0] = 4;  nkList[0] = 29;
    bandList[1] = 2; ksList[1] = 32; nkList[1] = 33;
    bandList[2] = 3; ksList[2] = 64; nkList[2] = 41;
  } else if (split == 1) {
    nb = 1; bandList[0] = 4; ksList[0] = 104; nkList[0] = 137;
  } else {
    nb = 1; bandList[0] = 5; ksList[0] = 240; nkList[0] = 121;
  }
  for (int bi = 0; bi < nb; ++bi) {
    int band = bandList[bi], ks = ksList[bi], nk = nkList[bi];
    float ar[16], ai[16];
#pragma unroll
    for (int c = 0; c < 16; ++c) { ar[c] = 0.f; ai[c] = 0.f; }
    for (int c0 = 0; c0 < nk; c0 += CS) {
      int kc = min(CS, nk - c0);
      __syncthreads();
      {
        const float4* srcp = (const float4*)(coef + (size_t)(bside * 357 + (ks - 4) + c0) * 128);
        for (int idx = threadIdx.x; idx < kc * 32; idx += 256)
          ((float4*)Fs)[idx] = srcp[idx];
      }
      __syncthreads();
      float Wr, Wi; { int m = ((ks + c0) * t) & 2047; sincosf((float)m * PI2_N, &Wi, &Wr); }
      const float* Fb = Fs + ch0 * 2;
#pragma unroll 2
      for (int kk = 0; kk < kc; ++kk) {
        const float* F = Fb + kk * 128;
#pragma unroll
        for (int q = 0; q < 8; ++q) {
          float4 Fv = *(const float4*)(F + q * 4);
          ar[2 * q]     = fmaf(Fv.x, Wr, ar[2 * q]);     ar[2 * q]     = fmaf(-Fv.y, Wi, ar[2 * q]);
          ai[2 * q]     = fmaf(Fv.x, Wi, ai[2 * q]);     ai[2 * q]     = fmaf( Fv.y, Wr, ai[2 * q]);
          ar[2 * q + 1] = fmaf(Fv.z, Wr, ar[2 * q + 1]); ar[2 * q + 1] = fmaf(-Fv.w, Wi, ar[2 * q + 1]);
          ai[2 * q + 1] = fmaf(Fv.z, Wi, ai[2 * q + 1]); ai[2 * q + 1] = fmaf( Fv.w, Wr, ai[2 * q + 1]);
        }
        float nr = fmaf(Wr, Rr, -(Wi * Ri));
        float ni = fmaf(Wr, Ri, Wi * Rr);
        Wr = nr; Wi = ni;
      }
    }
    __syncthreads();
#pragma unroll
    for (int c = 0; c < 16; ++c) {
      Lt[0][ch0 + c][lane] = ar[c] * (1.f / 1024.f);
      Lt[1][ch0 + c][lane] = ai[c] * (1.f / 1024.f);
    }
    __syncthreads();
    size_t base = (size_t)((band * 8 + bside) * 2) * 131072 + (size_t)tchunk * 4096;
    for (int idx = threadIdx.x; idx < 2048; idx += 256) {
      int fi = idx >> 10, r = idx & 1023, tt = r >> 4, c4 = (r & 15) * 4;
      float4 v = make_float4(Lt[fi][c4][tt], Lt[fi][c4 + 1][tt], Lt[fi][c4 + 2][tt], Lt[fi][c4 + 3][tt]);
      *(float4*)(fields + base + (size_t)fi * 131072 + tt * 64 + c4) = v;
    }
  }
}

// ---------------- K2b: band 0 = sum(bands 1..5) - duplicated boundary bins.
__global__ __launch_bounds__(256) void k_band0(const float* __restrict__ fields_in,
                                               const float* __restrict__ coef,
                                               float* __restrict__ fields) {
  int idx = blockIdx.x * 256 + threadIdx.x;  // 1048576 = 8 bsd x 2048 t x 64 ch
  int ch = idx & 63, t = (idx >> 6) & 2047, bsd = idx >> 17;
  size_t o = (size_t)t * 64 + ch;
  float re = 0.f, im = 0.f;
#pragma unroll
  for (int b = 1; b <= 5; ++b) {
    re += fields_in[(size_t)((b * 8 + bsd) * 2 + 0) * 131072 + o];
    im += fields_in[(size_t)((b * 8 + bsd) * 2 + 1) * 131072 + o];
  }
  const int dk[4] = {32, 64, 104, 240};
#pragma unroll
  for (int q = 0; q < 4; ++q) {
    int k = dk[q];
    const float* F = coef + ((size_t)(bsd * 357 + (k - 4)) * 64 + ch) * 2;
    float fx = F[0], fy = F[1];
    float s, c; sincosf((float)((k * t) & 2047) * PI2_N, &s, &c);
    re -= (fx * c - fy * s) * (1.f / 1024.f);
    im -= (fx * s + fy * c) * (1.f / 1024.f);
  }
  fields[(size_t)(bsd * 2 + 0) * 131072 + o] = re;
  fields[(size_t)(bsd * 2 + 1) * 131072 + o] = im;
}

// ---------------- K4: fused pairwise sums; trig expansion on the fly.
// Grid (32, 24): 64 t-samples per block. LDS rows padded to 68 (bank-safe).
// part[((bb*32+ts)*7 + a)*4096 + i*64 + j]
__global__ __launch_bounds__(256) void k_pairs(const float* __restrict__ fields,
                                               float* __restrict__ part) {
  __shared__ float le[2][4][16][68];  // [side][f][tt][ch pad 68]  (34.8 KB)
  int ts = blockIdx.x, bb = blockIdx.y;
  int band = bb >> 2, b = bb & 3;
  int tid = threadIdx.x;
  int ti = tid >> 4, tj = tid & 15;
  const float* bi = fields + (size_t)((band * 8 + b * 2 + 0) * 2) * 131072;
  const float* bj = fields + (size_t)((band * 8 + b * 2 + 1) * 2) * 131072;
  float acc[7][4][4];
#pragma unroll
  for (int a = 0; a < 7; ++a)
#pragma unroll
    for (int il = 0; il < 4; ++il)
#pragma unroll
      for (int jl = 0; jl < 4; ++jl) acc[a][il][jl] = 0.f;
  int lside = tid >> 7, lr = tid & 127, ltt = lr >> 3, lc8 = (lr & 7) * 8;
  const float* lbase = lside ? bj : bi;
  int tb = ts * 64;
  for (int sub = 0; sub < 4; ++sub) {
    int t0 = tb + sub * 16;
    {
      const float* rp = lbase + (size_t)(t0 + ltt) * 64 + lc8;
      float4 reA = *(const float4*)rp;
      float4 reB = *(const float4*)(rp + 4);
      float4 imA = *(const float4*)(rp + 131072);
      float4 imB = *(const float4*)(rp + 131072 + 4);
      float re8[8] = {reA.x, reA.y, reA.z, reA.w, reB.x, reB.y, reB.z, reB.w};
      float im8[8] = {imA.x, imA.y, imA.z, imA.w, imB.x, imB.y, imB.z, imB.w};
#pragma unroll
      for (int e = 0; e < 8; ++e) {
        float re = re8[e], im = im8[e];
        float mag2 = fmaf(re, re, im * im);
        float rinv = mag2 > 0.f ? rsqrtf(mag2) : 0.f;
        float cc = mag2 > 0.f ? re * rinv : 1.f;
        float ss = im * rinv;
        float ph = atan2f(im, re);
        le[lside][0][ltt][lc8 + e] = ph;
        le[lside][1][ltt][lc8 + e] = cc;
        le[lside][2][ltt][lc8 + e] = ss;
        le[lside][3][ltt][lc8 + e] = re;
      }
    }
    __syncthreads();
#pragma unroll 2
    for (int tt = 0; tt < 16; ++tt) {
      float4 vph1 = *(const float4*)&le[0][0][tt][ti * 4];
      float4 vc1 = *(const float4*)&le[0][1][tt][ti * 4];
      float4 vs1 = *(const float4*)&le[0][2][tt][ti * 4];
      float4 vf1 = *(const float4*)&le[0][3][tt][ti * 4];
      float4 vph2 = *(const float4*)&le[1][0][tt][tj * 4];
      float4 vc2 = *(const float4*)&le[1][1][tt][tj * 4];
      float4 vs2 = *(const float4*)&le[1][2][tt][tj * 4];
      float4 vf2 = *(const float4*)&le[1][3][tt][tj * 4];
      float ph1a[4] = {vph1.x, vph1.y, vph1.z, vph1.w};
      float c1a[4] = {vc1.x, vc1.y, vc1.z, vc1.w};
      float s1a[4] = {vs1.x, vs1.y, vs1.z, vs1.w};
      float f1a[4] = {vf1.x, vf1.y, vf1.z, vf1.w};
      float ph2a[4] = {vph2.x, vph2.y, vph2.z, vph2.w};
      float c2a[4] = {vc2.x, vc2.y, vc2.z, vc2.w};
      float s2a[4] = {vs2.x, vs2.y, vs2.z, vs2.w};
      float f2a[4] = {vf2.x, vf2.y, vf2.z, vf2.w};
      float p1a[4] = {f1a[0] * f1a[0], f1a[1] * f1a[1], f1a[2] * f1a[2], f1a[3] * f1a[3]};
      float p2a[4] = {f2a[0] * f2a[0], f2a[1] * f2a[1], f2a[2] * f2a[2], f2a[3] * f2a[3]};
#pragma unroll
      for (int il = 0; il < 4; ++il) {
#pragma unroll
        for (int jl = 0; jl < 4; ++jl) {
          float pd = ph1a[il] - ph2a[jl];
          float sg = pd > 0.f ? 1.f : -1.f;
          acc[2][il][jl] += sg;
          acc[3][il][jl] = fmaf(sg, p1a[il], acc[3][il][jl]);
          acc[4][il][jl] = fmaf(sg, p2a[jl], acc[4][il][jl]);
          acc[5][il][jl] += fabsf(pd);
          acc[0][il][jl] = fmaf(c1a[il], c2a[jl], acc[0][il][jl]);
          acc[0][il][jl] = fmaf(s1a[il], s2a[jl], acc[0][il][jl]);
          acc[1][il][jl] = fmaf(s1a[il], c2a[jl], acc[1][il][jl]);
          acc[1][il][jl] = fmaf(-c1a[il], s2a[jl], acc[1][il][jl]);
          acc[6][il][jl] = fmaf(p1a[il], p2a[jl], acc[6][il][jl]);
        }
      }
    }
    __syncthreads();
  }
  int pb = (bb * 32 + ts) * 7;
#pragma unroll
  for (int a = 0; a < 7; ++a)
#pragma unroll
    for (int il = 0; il < 4; ++il) {
      int ro = (ti * 4 + il) * 64 + tj * 4;
      *(float4*)&part[(size_t)(pb + a) * 4096 + ro] =
          make_float4(acc[a][il][0], acc[a][il][1], acc[a][il][2], acc[a][il][3]);
    }
}

// ---------------- K3: per-signal stats: Sum f^2 (Parseval), Sum f^4 (from fields).
__global__ __launch_bounds__(256) void k_stats(const float* __restrict__ fields,
                                               const float* __restrict__ pwr,
                                               float* __restrict__ stats) {
  __shared__ float red[256];
  int bb = blockIdx.x;               // 48 = band(6) x bsd(8)
  int band = bb >> 3, bsd = bb & 7;
  int ch = threadIdx.x & 63, tq = threadIdx.x >> 6;
  const float* fp = fields + (size_t)((band * 8 + bsd) * 2) * 131072 + (size_t)tq * 512 * 64 + ch;
  float s4 = 0.f;
  for (int tt = 0; tt < 512; ++tt) { float v = fp[tt * 64]; float p = v * v; s4 = fmaf(p, p, s4); }
  red[threadIdx.x] = s4;
  __syncthreads();
  if (tq == 0) {
    float sq = red[ch] + red[64 + ch] + red[128 + ch] + red[192 + ch];
    int kl = c_klo[band] - 4, nk = c_nk[band];
    const float* pp = pwr + (size_t)(bsd * 357 + kl) * 64 + ch;
    float sp = 0.f;
    for (int kkq = 0; kkq < nk; ++kkq) sp += pp[kkq * 64];
    sp *= (1.f / 1024.f);
    int o = ((band * 8 + bsd) * 64 + ch) * 2;
    stats[o] = sp;
    stats[o + 1] = sq;
  }
}

// ---------------- K5: reduce partials + coherence + spectral tcorr + finalize.
__global__ __launch_bounds__(256) void k_final(const float* __restrict__ part,
                                               const float* __restrict__ stats,
                                               const float* __restrict__ pwr,
                                               const float* __restrict__ coef,
                                               float* __restrict__ out) {
  int gid = blockIdx.x * 256 + threadIdx.x;  // 98304 = 24*4096
  int bb = gid >> 12, rem = gid & 4095;
  int band = bb >> 2, b = bb & 3;
  int i = rem >> 6, j = rem & 63;
  float S[7];
#pragma unroll
  for (int a = 0; a < 7; ++a) S[a] = 0.f;
  const float* pp = part + (size_t)bb * 32 * 7 * 4096 + rem;
  for (int ts = 0; ts < 32; ++ts)
#pragma unroll
    for (int a = 0; a < 7; ++a) S[a] += pp[(ts * 7 + a) * 4096];
  const float* st1 = stats + (size_t)((band * 8 + b * 2 + 0) * 64 + i) * 2;
  const float* st2 = stats + (size_t)((band * 8 + b * 2 + 1) * 64 + j) * 2;
  float sp1 = st1[0], sq1 = st1[1];
  float sp2 = st2[0], sq2 = st2[1];
  const float T = 2048.f, Ti = 1.f / 2048.f, Vi = 1.f / 2047.f;
  float plv = sqrtf(S[0] * S[0] + S[1] * S[1]) * Ti;
  float pli = fabsf(S[2]) * Ti;
  float wpli = fabsf(0.5f * (S[3] + S[4])) / (0.5f * (sp1 + sp2) + 1e-8f);
  int kl = c_klo[band] - 4, n = c_nk[band];
  const float* P1 = pwr + (size_t)((b * 2 + 0) * 357 + kl) * 64 + i;
  const float* P2 = pwr + (size_t)((b * 2 + 1) * 357 + kl) * 64 + j;
  const float* C1 = coef + ((size_t)((b * 2 + 0) * 357 + kl) * 64 + i) * 2;
  const float* C2 = coef + ((size_t)((b * 2 + 1) * 357 + kl) * 64 + j) * 2;
  float coh = 0.f, cross = 0.f;
  for (int kkq = 0; kkq < n; ++kkq) {
    float r = P1[kkq * 64] * P2[kkq * 64];
    coh += __fdividef(r, r + 1e-8f);
    float2 a = *(const float2*)(C1 + kkq * 128);
    float2 c = *(const float2*)(C2 + kkq * 128);
    cross = fmaf(a.x, c.x, fmaf(a.y, c.y, cross));
  }
  coh *= (1.f / 1025.f);
  float mp1 = sp1 * Ti, mp2 = sp2 * Ti;
  float sd1 = sqrtf(fmaxf((sq1 - T * mp1 * mp1) * Vi, 0.f));
  float sd2 = sqrtf(fmaxf((sq2 - T * mp2 * mp2) * Vi, 0.f));
  float pcorr = (S[6] - T * mp1 * mp2) / ((sd1 + 1e-8f) * (sd2 + 1e-8f)) * Ti;
  float phd = S[5] * Ti;
  float se1 = sqrtf(sp1 * Vi);
  float se2 = sqrtf(sp2 * Vi);
  float tcorr = (cross * (1.f / 1024.f)) / ((se1 + 1e-8f) * (se2 + 1e-8f)) * Ti;
  size_t ob = (size_t)((b * 6 + band) * 7) * 4096 + rem;
  out[ob] = plv;
  out[ob + 4096] = pli;
  out[ob + 2 * 4096] = wpli;
  out[ob + 3 * 4096] = coh;
  out[ob + 4 * 4096] = pcorr;
  out[ob + 5 * 4096] = phd;
  out[ob + 6 * 4096] = tcorr;
}

extern "C" void kernel_launch(void* const* d_in, const int* in_sizes, int n_in,
                              void* d_out, int out_size, void* d_ws, size_t ws_size,
                              hipStream_t stream) {
  const float* e1 = (const float*)d_in[0];
  const float* e2 = (const float*)d_in[1];
  float* out = (float*)d_out;
  char* ws = (char*)d_ws;
  size_t off = 0;
  auto alloc = [&](size_t bytes) -> void* {
    void* p = ws + off;
    off += (bytes + 255) & ~(size_t)255;
    return p;
  };
  float2* coef = (float2*)alloc((size_t)8 * 357 * 64 * 8);          // 1.46 MB
  float* pwr = (float*)alloc((size_t)8 * 357 * 64 * 4);             // 0.73 MB
  float* fields = (float*)alloc((size_t)6 * 8 * 2 * 131072 * 4);    // 50.3 MB
  float* stats = (float*)alloc((size_t)6 * 8 * 64 * 2 * 4);         // 25 KB
  float* part = (float*)alloc((size_t)24 * 32 * 7 * 4096 * 4);      // 88.1 MB
  (void)in_sizes; (void)n_in; (void)out_size; (void)ws_size;       // total ~140.6 MB

  hipLaunchKernelGGL(k_dft, dim3(512), dim3(256), 0, stream, e1, e2, coef, pwr);
  hipLaunchKernelGGL(k_analytic, dim3(32, 8, 3), dim3(256), 0, stream, (const float*)coef, fields);
  hipLaunchKernelGGL(k_band0, dim3(4096), dim3(256), 0, stream, fields, (const float*)coef, fields);
  hipLaunchKernelGGL(k_pairs, dim3(32, 24), dim3(256), 0, stream, fields, part);
  hipLaunchKernelGGL(k_stats, dim3(48), dim3(256), 0, stream, fields, pwr, stats);
  hipLaunchKernelGGL(k_final, dim3(384), dim3(256), 0, stream, part, stats, pwr, (const float*)coef, out);
}